// Round 1
// baseline (1199.293 us; speedup 1.0000x reference)
//
#include <hip/hip_runtime.h>
#include <hip/hip_bf16.h>

#define VXX 256
#define VYY 256
#define VZZ 20
#define NC  80
#define OH  200
#define OW  200
#define OZ  16
#define SPATIAL (OH*OW*OZ)      // 640000
#define NVOX (VXX*VYY*VZZ)      // 1310720
#define EPSV 1e-5f

__global__ void init_winner_k(int* __restrict__ w) {
    int i = blockIdx.x * 256 + threadIdx.x;
    if (i < NVOX) w[i] = -1;
}

__global__ void scatter_k(const int* __restrict__ coords, int npts,
                          int* __restrict__ winner) {
    int i = blockIdx.x * 256 + threadIdx.x;
    if (i >= npts) return;
    int b = coords[i*4+0];
    int x = coords[i*4+1];
    int y = coords[i*4+2];
    int z = coords[i*4+3];
    int vi = ((b*VXX + x)*VYY + y)*VZZ + z;
    atomicMax(&winner[vi], i);   // max point index == last write wins
}

__launch_bounds__(256)
__global__ void fused_k(const float* __restrict__ bev,
                        const float* __restrict__ feats,
                        const float* __restrict__ wconv,
                        const float* __restrict__ bconv,
                        const float* __restrict__ gamma,
                        const float* __restrict__ beta,
                        const float* __restrict__ mean,
                        const float* __restrict__ var,
                        const int*  __restrict__ winner,
                        float* __restrict__ out) {
    __shared__ float xt[2*NC][64];      // rows 0..79: bev, rows 80..159: prior
    __shared__ int   s_pidx[8][64];
    __shared__ float s_pw[8][64];

    const int tid   = threadIdx.x;
    const int sbase = blockIdx.x * 64;  // 64 spatial positions per block
    const int s     = tid & 63;
    const int grp   = tid >> 6;         // 0..3

    // ---------- Phase A: tap geometry + winner gather ----------
    {
        int S  = sbase + s;
        int z  = S & 15;                // OZ = 16
        int wq = (S >> 4) % OW;
        int h  = S / (OZ * OW);

        float posy = (h + 0.5f) * ((float)VYY / (float)OH) - 0.5f;   // h -> Y axis
        posy = fminf(fmaxf(posy, 0.f), (float)(VYY - 1));
        int   y0 = (int)posy; int y1 = min(y0 + 1, VYY - 1); float fy = posy - (float)y0;

        float posx = (wq + 0.5f) * ((float)VXX / (float)OW) - 0.5f;  // w -> X axis
        posx = fminf(fmaxf(posx, 0.f), (float)(VXX - 1));
        int   x0 = (int)posx; int x1 = min(x0 + 1, VXX - 1); float fx = posx - (float)x0;

        float posz = (z + 0.5f) * ((float)VZZ / (float)OZ) - 0.5f;
        posz = fminf(fmaxf(posz, 0.f), (float)(VZZ - 1));
        int   z0 = (int)posz; int z1 = min(z0 + 1, VZZ - 1); float fz = posz - (float)z0;

        #pragma unroll
        for (int kk = 0; kk < 2; ++kk) {
            int k  = grp * 2 + kk;            // 0..7
            int kz = k & 1, kx = (k >> 1) & 1, ky = k >> 2;
            int yy = ky ? y1 : y0;
            int xx = kx ? x1 : x0;
            int zz = kz ? z1 : z0;
            float wt = (ky ? fy : 1.f - fy) * (kx ? fx : 1.f - fx) * (kz ? fz : 1.f - fz);
            int vi = (xx * VYY + yy) * VZZ + zz;   // batch 0
            s_pidx[k][s] = winner[vi];
            s_pw[k][s]   = wt;
        }
    }

    // ---------- Phase B: stage bev tile (rows 0..79) ----------
    #pragma unroll
    for (int j = 0; j < 20; ++j) {
        int c = grp + j * 4;
        xt[c][s] = bev[c * SPATIAL + sbase + s];
    }

    __syncthreads();

    // ---------- Phase C: prior tile (rows 80..159) via tap gather ----------
    {
        int   pi[8]; float wt[8];
        #pragma unroll
        for (int k = 0; k < 8; ++k) { pi[k] = s_pidx[k][s]; wt[k] = s_pw[k][s]; }
        #pragma unroll
        for (int j = 0; j < 20; ++j) {
            int c = grp * 20 + j;
            float acc = 0.f;
            #pragma unroll
            for (int k = 0; k < 8; ++k) {
                if (pi[k] >= 0) acc += wt[k] * feats[pi[k] * NC + c];
            }
            xt[NC + c][s] = acc;
        }
    }

    __syncthreads();

    // ---------- Phase D: 80x160 GEMM + BN + residual + ReLU ----------
    const int ogrp = tid & 15;
    const int sgrp = tid >> 4;
    const int o0 = ogrp * 5;
    const int s0 = sgrp * 4;

    float acc[5][4];
    #pragma unroll
    for (int i = 0; i < 5; ++i)
        #pragma unroll
        for (int j = 0; j < 4; ++j) acc[i][j] = 0.f;

    for (int cq = 0; cq < 40; ++cq) {
        float4 xv[4];
        #pragma unroll
        for (int jj = 0; jj < 4; ++jj)
            xv[jj] = *(const float4*)&xt[cq * 4 + jj][s0];
        #pragma unroll
        for (int i = 0; i < 5; ++i) {
            float4 wv = *(const float4*)&wconv[(o0 + i) * 160 + cq * 4];
            acc[i][0] += wv.x * xv[0].x + wv.y * xv[1].x + wv.z * xv[2].x + wv.w * xv[3].x;
            acc[i][1] += wv.x * xv[0].y + wv.y * xv[1].y + wv.z * xv[2].y + wv.w * xv[3].y;
            acc[i][2] += wv.x * xv[0].z + wv.y * xv[1].z + wv.z * xv[2].z + wv.w * xv[3].z;
            acc[i][3] += wv.x * xv[0].w + wv.y * xv[1].w + wv.z * xv[2].w + wv.w * xv[3].w;
        }
    }

    #pragma unroll
    for (int i = 0; i < 5; ++i) {
        int o = o0 + i;
        float bc  = bconv[o];
        float inv = gamma[o] * rsqrtf(var[o] + EPSV);
        float sh  = beta[o] - mean[o] * inv;
        float4 r  = *(const float4*)&xt[o][s0];   // bev residual from LDS
        float4 v;
        v.x = fmaxf((acc[i][0] + bc) * inv + sh + r.x, 0.f);
        v.y = fmaxf((acc[i][1] + bc) * inv + sh + r.y, 0.f);
        v.z = fmaxf((acc[i][2] + bc) * inv + sh + r.z, 0.f);
        v.w = fmaxf((acc[i][3] + bc) * inv + sh + r.w, 0.f);
        *(float4*)&out[o * SPATIAL + sbase + s0] = v;
    }
}

extern "C" void kernel_launch(void* const* d_in, const int* in_sizes, int n_in,
                              void* d_out, int out_size, void* d_ws, size_t ws_size,
                              hipStream_t stream) {
    const float* bev    = (const float*)d_in[0];
    const int*   coords = (const int*)  d_in[1];
    const float* feats  = (const float*)d_in[2];
    const float* wconv  = (const float*)d_in[3];
    const float* bconv  = (const float*)d_in[4];
    const float* gamma  = (const float*)d_in[5];
    const float* beta   = (const float*)d_in[6];
    const float* mean   = (const float*)d_in[7];
    const float* var    = (const float*)d_in[8];
    float*       out    = (float*)d_out;
    int*         winner = (int*)d_ws;           // 1310720 ints = 5.24 MB
    int npts = in_sizes[1] / 4;

    hipLaunchKernelGGL(init_winner_k, dim3((NVOX + 255) / 256), dim3(256), 0, stream, winner);
    hipLaunchKernelGGL(scatter_k, dim3((npts + 255) / 256), dim3(256), 0, stream,
                       coords, npts, winner);
    hipLaunchKernelGGL(fused_k, dim3(SPATIAL / 64), dim3(256), 0, stream,
                       bev, feats, wconv, bconv, gamma, beta, mean, var, winner, out);
}

// Round 2
// 309.477 us; speedup vs baseline: 3.8752x; 3.8752x over previous
//
#include <hip/hip_runtime.h>
#include <hip/hip_bf16.h>

#define VXX 256
#define VYY 256
#define VZZ 20
#define NC  80
#define OH  200
#define OW  200
#define OZ  16
#define SPATIAL (OH*OW*OZ)      // 640000
#define NVOX (VXX*VYY*VZZ)      // 1310720
#define EPSV 1e-5f
#define NS 128                  // spatial positions per block
#define RS 168                  // x_lds row stride in bf16 elems (336 B = 21*16 B)

typedef float  f32x4 __attribute__((ext_vector_type(4)));
typedef short  s16x8 __attribute__((ext_vector_type(8)));

__device__ __forceinline__ ushort f2bf(float f) {
    uint u = __builtin_bit_cast(uint, f);
    u += 0x7FFFu + ((u >> 16) & 1u);     // round-to-nearest-even
    return (ushort)(u >> 16);
}

__global__ void init_winner_k(int* __restrict__ w) {
    int i = blockIdx.x * 256 + threadIdx.x;
    if (i < NVOX) w[i] = -1;
}

__global__ void scatter_k(const int* __restrict__ coords, int npts,
                          int* __restrict__ winner) {
    int i = blockIdx.x * 256 + threadIdx.x;
    if (i >= npts) return;
    int b = coords[i*4+0];
    int x = coords[i*4+1];
    int y = coords[i*4+2];
    int z = coords[i*4+3];
    int vi = ((b*VXX + x)*VYY + y)*VZZ + z;
    atomicMax(&winner[vi], i);   // max point index == last write wins
}

// Pack W (80x160 fp32) into bf16 MFMA A-fragment order; fold BN into (scale, shift).
// Fragment f = mt*5+ks holds A[o = mt*16 + (l&15)][c = ks*32 + (l>>4)*8 + j].
__global__ void prep_k(const float* __restrict__ wconv,
                       const float* __restrict__ bconv,
                       const float* __restrict__ gamma,
                       const float* __restrict__ beta,
                       const float* __restrict__ mean,
                       const float* __restrict__ var,
                       ushort* __restrict__ wfrag,
                       float2* __restrict__ bnss) {
    int tid = threadIdx.x;
    for (int idx = tid; idx < 25*512; idx += 256) {
        int f   = idx >> 9;
        int rem = idx & 511;
        int l   = rem >> 3;
        int j   = rem & 7;
        int mt  = f / 5;
        int ks  = f - mt*5;
        int o   = mt*16 + (l & 15);
        int c   = ks*32 + (l >> 4)*8 + j;
        wfrag[idx] = f2bf(wconv[o*160 + c]);
    }
    if (tid < NC) {
        float inv = gamma[tid] * rsqrtf(var[tid] + EPSV);
        bnss[tid] = make_float2(inv, bconv[tid]*inv + beta[tid] - mean[tid]*inv);
    }
}

__launch_bounds__(256)
__global__ void fused_k(const float* __restrict__ bev,
                        const float* __restrict__ feats,
                        const int*  __restrict__ winner,
                        const ushort* __restrict__ wfrag,
                        const float2* __restrict__ bnss,
                        float* __restrict__ out) {
    __shared__ __align__(16) ushort x_lds[NS * RS];   // [s][c] bf16, 42 KB

    const int tid   = threadIdx.x;
    const int sbase = blockIdx.x * NS;

    // ---------- Phase B: bev -> x_lds[s][0..79] ----------
    #pragma unroll
    for (int it = 0; it < 10; ++it) {
        int idx = tid + it*256;          // 0..2559 = 80 c * 32 s-quads
        int c   = idx % 80;
        int sq  = idx / 80;
        const float4 v = *(const float4*)&bev[c*SPATIAL + sbase + sq*4];
        int s0 = sq*4;
        x_lds[(s0+0)*RS + c] = f2bf(v.x);
        x_lds[(s0+1)*RS + c] = f2bf(v.y);
        x_lds[(s0+2)*RS + c] = f2bf(v.z);
        x_lds[(s0+3)*RS + c] = f2bf(v.w);
    }

    // ---------- Phase C: gather prior -> x_lds[s][80..159] ----------
    {
        const int sl   = tid & 127;
        const int half = tid >> 7;       // 0: c 80..119, 1: c 120..159
        const int S = sbase + sl;
        const int z = S & 15;
        const int w = (S >> 4) % OW;
        const int h = S / (OW * OZ);     // uniform within block (3200 % 128 == 0)

        float posy = (h + 0.5f) * ((float)VYY/(float)OH) - 0.5f;
        posy = fminf(fmaxf(posy, 0.f), (float)(VYY-1));
        int y0 = (int)posy; int y1 = min(y0+1, VYY-1); float fy = posy - (float)y0;
        float posx = (w + 0.5f) * ((float)VXX/(float)OW) - 0.5f;
        posx = fminf(fmaxf(posx, 0.f), (float)(VXX-1));
        int x0 = (int)posx; int x1 = min(x0+1, VXX-1); float fx = posx - (float)x0;
        float posz = (z + 0.5f) * ((float)VZZ/(float)OZ) - 0.5f;
        posz = fminf(fmaxf(posz, 0.f), (float)(VZZ-1));
        int z0 = (int)posz; int z1 = min(z0+1, VZZ-1); float fz = posz - (float)z0;

        int pi[8]; float wt[8];
        #pragma unroll
        for (int k = 0; k < 8; ++k) {
            int kz = k & 1, kx = (k>>1)&1, ky = k>>2;
            int yy = ky ? y1 : y0, xx = kx ? x1 : x0, zz = kz ? z1 : z0;
            pi[k] = winner[(xx*VYY + yy)*VZZ + zz];
            wt[k] = (ky?fy:1.f-fy) * (kx?fx:1.f-fx) * (kz?fz:1.f-fz);
        }

        const float4* feats4 = (const float4*)feats;
        #pragma unroll
        for (int q = 0; q < 10; ++q) {
            float ax=0.f, ay=0.f, az=0.f, aw=0.f;
            #pragma unroll
            for (int k = 0; k < 8; ++k) {
                if (pi[k] >= 0) {
                    float4 f = feats4[pi[k]*20 + half*10 + q];
                    ax += wt[k]*f.x; ay += wt[k]*f.y;
                    az += wt[k]*f.z; aw += wt[k]*f.w;
                }
            }
            int c = 80 + half*40 + q*4;
            ushort4 pk = make_ushort4(f2bf(ax), f2bf(ay), f2bf(az), f2bf(aw));
            *(ushort4*)&x_lds[sl*RS + c] = pk;   // 8 B, aligned
        }
    }

    __syncthreads();

    // ---------- Phase D: MFMA GEMM  y[o][s] = sum_c W[o][c] * x[c][s] ----------
    const int wave = tid >> 6, lane = tid & 63;
    const int lrow = lane & 15, lgrp = lane >> 4;

    f32x4 acc[2][5];
    #pragma unroll
    for (int nt = 0; nt < 2; ++nt)
        #pragma unroll
        for (int mt = 0; mt < 5; ++mt)
            acc[nt][mt] = (f32x4){0.f, 0.f, 0.f, 0.f};

    const int srow0 = (wave*32 +      lrow) * RS;
    const int srow1 = (wave*32 + 16 + lrow) * RS;

    #pragma unroll
    for (int ks = 0; ks < 5; ++ks) {
        s16x8 b0 = *(const s16x8*)&x_lds[srow0 + ks*32 + lgrp*8];
        s16x8 b1 = *(const s16x8*)&x_lds[srow1 + ks*32 + lgrp*8];
        #pragma unroll
        for (int mt = 0; mt < 5; ++mt) {
            s16x8 a = *(const s16x8*)&wfrag[((mt*5 + ks)*64 + lane)*8];
            acc[0][mt] = __builtin_amdgcn_mfma_f32_16x16x32_bf16(a, b0, acc[0][mt], 0, 0, 0);
            acc[1][mt] = __builtin_amdgcn_mfma_f32_16x16x32_bf16(a, b1, acc[1][mt], 0, 0, 0);
        }
    }

    // ---------- Epilogue: BN + residual + ReLU ----------
    #pragma unroll
    for (int mt = 0; mt < 5; ++mt) {
        #pragma unroll
        for (int nt = 0; nt < 2; ++nt) {
            int s = sbase + wave*32 + nt*16 + lrow;
            #pragma unroll
            for (int r = 0; r < 4; ++r) {
                int o = mt*16 + lgrp*4 + r;
                float2 ss = bnss[o];
                float v = acc[nt][mt][r]*ss.x + ss.y + bev[o*SPATIAL + s];
                out[o*SPATIAL + s] = fmaxf(v, 0.f);
            }
        }
    }
}

extern "C" void kernel_launch(void* const* d_in, const int* in_sizes, int n_in,
                              void* d_out, int out_size, void* d_ws, size_t ws_size,
                              hipStream_t stream) {
    const float* bev    = (const float*)d_in[0];
    const int*   coords = (const int*)  d_in[1];
    const float* feats  = (const float*)d_in[2];
    const float* wconv  = (const float*)d_in[3];
    const float* bconv  = (const float*)d_in[4];
    const float* gamma  = (const float*)d_in[5];
    const float* beta   = (const float*)d_in[6];
    const float* mean   = (const float*)d_in[7];
    const float* var    = (const float*)d_in[8];
    float*       out    = (float*)d_out;

    int*    winner = (int*)d_ws;                                   // 5,242,880 B
    ushort* wfrag  = (ushort*)((char*)d_ws + (size_t)NVOX*4);      // 25,600 B
    float2* bnss   = (float2*)((char*)d_ws + (size_t)NVOX*4 + 25600); // 640 B
    int npts = in_sizes[1] / 4;

    hipLaunchKernelGGL(init_winner_k, dim3((NVOX + 255)/256), dim3(256), 0, stream, winner);
    hipLaunchKernelGGL(scatter_k, dim3((npts + 255)/256), dim3(256), 0, stream,
                       coords, npts, winner);
    hipLaunchKernelGGL(prep_k, dim3(1), dim3(256), 0, stream,
                       wconv, bconv, gamma, beta, mean, var, wfrag, bnss);
    hipLaunchKernelGGL(fused_k, dim3(SPATIAL/NS), dim3(256), 0, stream,
                       bev, feats, winner, wfrag, bnss, out);
}

// Round 3
// 233.994 us; speedup vs baseline: 5.1253x; 1.3226x over previous
//
#include <hip/hip_runtime.h>
#include <hip/hip_bf16.h>

#define VXX 256
#define VYY 256
#define VZZ 20
#define NC  80
#define OH  200
#define OW  200
#define OZ  16
#define SPATIAL (OH*OW*OZ)      // 640000
#define NVOX (VXX*VYY*VZZ)      // 1310720
#define EPSV 1e-5f
#define NS 128                  // spatial positions per block
#define RS 168                  // x_lds row stride in bf16 elems (336 B)

typedef float  f32x4 __attribute__((ext_vector_type(4)));
typedef short  s16x8 __attribute__((ext_vector_type(8)));

__device__ __forceinline__ ushort f2bf(float f) {
    uint u = __builtin_bit_cast(uint, f);
    u += 0x7FFFu + ((u >> 16) & 1u);     // round-to-nearest-even
    return (ushort)(u >> 16);
}

__global__ void init_winner_k(int* __restrict__ w) {
    int i = blockIdx.x * 256 + threadIdx.x;
    if (i < NVOX) w[i] = -1;
}

__global__ void scatter_k(const int* __restrict__ coords, int npts,
                          int* __restrict__ winner) {
    int i = blockIdx.x * 256 + threadIdx.x;
    if (i >= npts) return;
    int b = coords[i*4+0];
    int x = coords[i*4+1];
    int y = coords[i*4+2];
    int z = coords[i*4+3];
    int vi = ((b*VXX + x)*VYY + y)*VZZ + z;
    atomicMax(&winner[vi], i);   // max point index == last write wins
}

// Pack W (80x160 fp32) into bf16 MFMA A-fragment order; fold BN into (scale, shift).
// Fragment f = mt*5+ks holds A[o = mt*16 + (l&15)][c = ks*32 + (l>>4)*8 + j].
__global__ void prep_k(const float* __restrict__ wconv,
                       const float* __restrict__ bconv,
                       const float* __restrict__ gamma,
                       const float* __restrict__ beta,
                       const float* __restrict__ mean,
                       const float* __restrict__ var,
                       ushort* __restrict__ wfrag,
                       float2* __restrict__ bnss) {
    int tid = threadIdx.x;
    for (int idx = tid; idx < 25*512; idx += 256) {
        int f   = idx >> 9;
        int rem = idx & 511;
        int l   = rem >> 3;
        int j   = rem & 7;
        int mt  = f / 5;
        int ks  = f - mt*5;
        int o   = mt*16 + (l & 15);
        int c   = ks*32 + (l >> 4)*8 + j;
        wfrag[idx] = f2bf(wconv[o*160 + c]);
    }
    if (tid < NC) {
        float inv = gamma[tid] * rsqrtf(var[tid] + EPSV);
        bnss[tid] = make_float2(inv, bconv[tid]*inv + beta[tid] - mean[tid]*inv);
    }
}

__launch_bounds__(512, 6)
__global__ void fused_k(const float* __restrict__ bev,
                        const float* __restrict__ feats,
                        const int*  __restrict__ winner,
                        const ushort* __restrict__ wfrag,
                        const float2* __restrict__ bnss,
                        float* __restrict__ out) {
    __shared__ __align__(16) ushort x_lds[NS * RS];   // [s][c] bf16, 42 KB

    const int tid   = threadIdx.x;
    const int sbase = blockIdx.x * NS;
    const int sl    = tid & 127;        // spatial position within tile
    const int quarter = tid >> 7;       // 0..3 -> 20 prior channels each

    // ---------- Phase A: tap geometry; ISSUE winner gather early ----------
    int pi[8]; float wt[8];
    {
        const int S = sbase + sl;
        const int z = S & 15;
        const int w = (S >> 4) % OW;
        const int h = S / (OW * OZ);     // uniform within block (3200 % 128 == 0)

        float posy = (h + 0.5f) * ((float)VYY/(float)OH) - 0.5f;
        posy = fminf(fmaxf(posy, 0.f), (float)(VYY-1));
        int y0 = (int)posy; int y1 = min(y0+1, VYY-1); float fy = posy - (float)y0;
        float posx = (w + 0.5f) * ((float)VXX/(float)OW) - 0.5f;
        posx = fminf(fmaxf(posx, 0.f), (float)(VXX-1));
        int x0 = (int)posx; int x1 = min(x0+1, VXX-1); float fx = posx - (float)x0;
        float posz = (z + 0.5f) * ((float)VZZ/(float)OZ) - 0.5f;
        posz = fminf(fmaxf(posz, 0.f), (float)(VZZ-1));
        int z0 = (int)posz; int z1 = min(z0+1, VZZ-1); float fz = posz - (float)z0;

        #pragma unroll
        for (int k = 0; k < 8; ++k) {
            int kz = k & 1, kx = (k>>1)&1, ky = k>>2;
            int yy = ky ? y1 : y0, xx = kx ? x1 : x0, zz = kz ? z1 : z0;
            pi[k] = winner[(xx*VYY + yy)*VZZ + zz];
            wt[k] = (ky?fy:1.f-fy) * (kx?fx:1.f-fx) * (kz?fz:1.f-fz);
        }
    }

    // ---------- Phase B: bev -> x_lds[s][0..79] (lane-coalesced) ----------
    #pragma unroll
    for (int it = 0; it < 5; ++it) {
        int idx = tid + it*512;          // 0..2559 = 80 c * 32 s-quads
        int sq  = idx & 31;              // consecutive lanes -> consecutive addrs
        int c   = idx >> 5;
        const float4 v = *(const float4*)&bev[c*SPATIAL + sbase + sq*4];
        int s0 = sq*4;
        x_lds[(s0+0)*RS + c] = f2bf(v.x);
        x_lds[(s0+1)*RS + c] = f2bf(v.y);
        x_lds[(s0+2)*RS + c] = f2bf(v.z);
        x_lds[(s0+3)*RS + c] = f2bf(v.w);
    }

    // ---------- Phase C: gather prior -> x_lds[s][80..159] ----------
    {
        const float4* feats4 = (const float4*)feats;
        #pragma unroll
        for (int q = 0; q < 5; ++q) {
            float ax=0.f, ay=0.f, az=0.f, aw=0.f;
            #pragma unroll
            for (int k = 0; k < 8; ++k) {
                if (pi[k] >= 0) {
                    float4 f = feats4[pi[k]*20 + quarter*5 + q];
                    ax += wt[k]*f.x; ay += wt[k]*f.y;
                    az += wt[k]*f.z; aw += wt[k]*f.w;
                }
            }
            int c = 80 + quarter*20 + q*4;
            ushort4 pk = make_ushort4(f2bf(ax), f2bf(ay), f2bf(az), f2bf(aw));
            *(ushort4*)&x_lds[sl*RS + c] = pk;   // 8 B, aligned
        }
    }

    __syncthreads();

    // ---------- Phase D: MFMA GEMM  y[o][s] = sum_c W[o][c] * x[c][s] ----------
    const int wave = tid >> 6, lane = tid & 63;
    const int lrow = lane & 15, lgrp = lane >> 4;

    f32x4 acc[5];
    #pragma unroll
    for (int mt = 0; mt < 5; ++mt) acc[mt] = (f32x4){0.f, 0.f, 0.f, 0.f};

    const int srow = (wave*16 + lrow) * RS;   // each wave owns a 16-s tile

    #pragma unroll
    for (int ks = 0; ks < 5; ++ks) {
        s16x8 b = *(const s16x8*)&x_lds[srow + ks*32 + lgrp*8];
        #pragma unroll
        for (int mt = 0; mt < 5; ++mt) {
            s16x8 a = *(const s16x8*)&wfrag[((mt*5 + ks)*64 + lane)*8];
            acc[mt] = __builtin_amdgcn_mfma_f32_16x16x32_bf16(a, b, acc[mt], 0, 0, 0);
        }
    }

    // ---------- Epilogue: BN + residual(from LDS bf16) + ReLU ----------
    const int slocal = wave*16 + lrow;
    const int sglob  = sbase + slocal;
    #pragma unroll
    for (int mt = 0; mt < 5; ++mt) {
        #pragma unroll
        for (int r = 0; r < 4; ++r) {
            int o = mt*16 + lgrp*4 + r;
            float2 ss = bnss[o];
            float resid = __builtin_bit_cast(float, (uint)x_lds[slocal*RS + o] << 16);
            float v = acc[mt][r]*ss.x + ss.y + resid;
            out[o*SPATIAL + sglob] = fmaxf(v, 0.f);
        }
    }
}

extern "C" void kernel_launch(void* const* d_in, const int* in_sizes, int n_in,
                              void* d_out, int out_size, void* d_ws, size_t ws_size,
                              hipStream_t stream) {
    const float* bev    = (const float*)d_in[0];
    const int*   coords = (const int*)  d_in[1];
    const float* feats  = (const float*)d_in[2];
    const float* wconv  = (const float*)d_in[3];
    const float* bconv  = (const float*)d_in[4];
    const float* gamma  = (const float*)d_in[5];
    const float* beta   = (const float*)d_in[6];
    const float* mean   = (const float*)d_in[7];
    const float* var    = (const float*)d_in[8];
    float*       out    = (float*)d_out;

    int*    winner = (int*)d_ws;                                      // 5,242,880 B
    ushort* wfrag  = (ushort*)((char*)d_ws + (size_t)NVOX*4);         // 25,600 B
    float2* bnss   = (float2*)((char*)d_ws + (size_t)NVOX*4 + 25600); // 640 B
    int npts = in_sizes[1] / 4;

    hipLaunchKernelGGL(init_winner_k, dim3((NVOX + 255)/256), dim3(256), 0, stream, winner);
    hipLaunchKernelGGL(scatter_k, dim3((npts + 255)/256), dim3(256), 0, stream,
                       coords, npts, winner);
    hipLaunchKernelGGL(prep_k, dim3(1), dim3(256), 0, stream,
                       wconv, bconv, gamma, beta, mean, var, wfrag, bnss);
    hipLaunchKernelGGL(fused_k, dim3(SPATIAL/NS), dim3(512), 0, stream,
                       bev, feats, winner, wfrag, bnss, out);
}

// Round 4
// 230.520 us; speedup vs baseline: 5.2026x; 1.0151x over previous
//
#include <hip/hip_runtime.h>
#include <hip/hip_bf16.h>

#define VXX 256
#define VYY 256
#define VZZ 20
#define NC  80
#define OH  200
#define OW  200
#define OZ  16
#define SPATIAL (OH*OW*OZ)      // 640000
#define NVOX (VXX*VYY*VZZ)      // 1310720
#define EPSV 1e-5f
#define NS 128                  // spatial positions per block
#define RS 168                  // x_lds row stride in bf16 elems (336 B)
#define NWG (SPATIAL/NS)        // 5000 blocks

typedef float  f32x4 __attribute__((ext_vector_type(4)));
typedef short  s16x8 __attribute__((ext_vector_type(8)));

__device__ __forceinline__ ushort f2bf(float f) {
    uint u = __builtin_bit_cast(uint, f);
    u += 0x7FFFu + ((u >> 16) & 1u);     // round-to-nearest-even
    return (ushort)(u >> 16);
}

__global__ void init_winner_k(int* __restrict__ w) {
    int i = blockIdx.x * 256 + threadIdx.x;
    if (i < NVOX) w[i] = -1;
}

__global__ void scatter_k(const int* __restrict__ coords, int npts,
                          int* __restrict__ winner) {
    int i = blockIdx.x * 256 + threadIdx.x;
    if (i >= npts) return;
    int b = coords[i*4+0];
    int x = coords[i*4+1];
    int y = coords[i*4+2];
    int z = coords[i*4+3];
    int vi = ((b*VXX + x)*VYY + y)*VZZ + z;
    atomicMax(&winner[vi], i);   // max point index == last write wins
}

// Pack W (80x160 fp32) into bf16 MFMA A-fragment order; fold BN into (scale, shift).
// Fragment f = mt*5+ks holds A[o = mt*16 + (l&15)][c = ks*32 + (l>>4)*8 + j].
__global__ void prep_k(const float* __restrict__ wconv,
                       const float* __restrict__ bconv,
                       const float* __restrict__ gamma,
                       const float* __restrict__ beta,
                       const float* __restrict__ mean,
                       const float* __restrict__ var,
                       ushort* __restrict__ wfrag,
                       float2* __restrict__ bnss) {
    int tid = threadIdx.x;
    for (int idx = tid; idx < 25*512; idx += 256) {
        int f   = idx >> 9;
        int rem = idx & 511;
        int l   = rem >> 3;
        int j   = rem & 7;
        int mt  = f / 5;
        int ks  = f - mt*5;
        int o   = mt*16 + (l & 15);
        int c   = ks*32 + (l >> 4)*8 + j;
        wfrag[idx] = f2bf(wconv[o*160 + c]);
    }
    if (tid < NC) {
        float inv = gamma[tid] * rsqrtf(var[tid] + EPSV);
        bnss[tid] = make_float2(inv, bconv[tid]*inv + beta[tid] - mean[tid]*inv);
    }
}

__launch_bounds__(512, 6)
__global__ void fused_k(const float* __restrict__ bev,
                        const float* __restrict__ feats,
                        const int*  __restrict__ winner,
                        const ushort* __restrict__ wfrag,
                        const float2* __restrict__ bnss,
                        float* __restrict__ out) {
    __shared__ __align__(16) ushort x_lds[NS * RS];   // [s][c] bf16, 42 KB

    const int tid   = threadIdx.x;
    // XCD-aware bijective swizzle: 5000 % 8 == 0 -> each XCD gets 625
    // consecutive tiles (25 full h-rows); winner slice per stripe ~650 KB -> L2.
    const int bid   = blockIdx.x;
    const int swzb  = (bid & 7) * (NWG/8) + (bid >> 3);
    const int sbase = swzb * NS;
    const int sl    = tid & 127;        // spatial position within tile
    const int quarter = tid >> 7;       // 0..3 -> 20 prior channels each

    // ---------- Phase A: tap geometry; ISSUE winner gather early ----------
    int pi[8]; float wt[8];
    {
        const int S = sbase + sl;
        const int z = S & 15;
        const int w = (S >> 4) % OW;
        const int h = S / (OW * OZ);     // uniform within block (3200 % 128 == 0)

        float posy = (h + 0.5f) * ((float)VYY/(float)OH) - 0.5f;
        posy = fminf(fmaxf(posy, 0.f), (float)(VYY-1));
        int y0 = (int)posy; int y1 = min(y0+1, VYY-1); float fy = posy - (float)y0;
        float posx = (w + 0.5f) * ((float)VXX/(float)OW) - 0.5f;
        posx = fminf(fmaxf(posx, 0.f), (float)(VXX-1));
        int x0 = (int)posx; int x1 = min(x0+1, VXX-1); float fx = posx - (float)x0;
        float posz = (z + 0.5f) * ((float)VZZ/(float)OZ) - 0.5f;
        posz = fminf(fmaxf(posz, 0.f), (float)(VZZ-1));
        int z0 = (int)posz; int z1 = min(z0+1, VZZ-1); float fz = posz - (float)z0;

        #pragma unroll
        for (int k = 0; k < 8; ++k) {
            int kz = k & 1, kx = (k>>1)&1, ky = k>>2;
            int yy = ky ? y1 : y0, xx = kx ? x1 : x0, zz = kz ? z1 : z0;
            pi[k] = winner[(xx*VYY + yy)*VZZ + zz];
            wt[k] = (ky?fy:1.f-fy) * (kx?fx:1.f-fx) * (kz?fz:1.f-fz);
        }
    }

    // ---------- Phase B: bev -> x_lds[s][0..79], shfl-transposed ----------
    // Wave handles 4 channels x 64 s per iter: lane (q16 = l&15, m = l>>4)
    // loads c = cbase+m, s-quad sq = sqh*16+q16 (coalesced 256B per m-group).
    // 4x4 transpose across lanes {q16, q16+16, q16+32, q16+48} -> lane writes
    // row s = 4*sq+m, cols cbase..cbase+3 as one b64 (conflict-free: 64
    // distinct rows, bank stride 20 -> 2-way max).
    {
        const int wv = tid >> 6, ln = tid & 63;
        const int q16 = ln & 15, mm = ln >> 4;
        #pragma unroll
        for (int it = 0; it < 5; ++it) {
            int g     = it*8 + wv;          // 0..39
            int cbase = (g >> 1) * 4;       // 0,4,...,76
            int sq    = (g & 1)*16 + q16;   // 0..31
            const float4 v = *(const float4*)&bev[(cbase+mm)*SPATIAL + sbase + sq*4];
            uint u0 = (uint)f2bf(v.x) | ((uint)f2bf(v.y) << 16);
            uint u1 = (uint)f2bf(v.z) | ((uint)f2bf(v.w) << 16);
            uint us[4];
            #pragma unroll
            for (int j = 0; j < 4; ++j) {
                int src = q16 + 16*j;
                uint t0 = (uint)__shfl((int)u0, src, 64);
                uint t1 = (uint)__shfl((int)u1, src, 64);
                uint sel = (mm & 2) ? t1 : t0;
                us[j] = (mm & 1) ? (sel >> 16) : (sel & 0xffffu);
            }
            uint2 o2 = make_uint2(us[0] | (us[1] << 16), us[2] | (us[3] << 16));
            int row = sq*4 + mm;
            *(uint2*)&x_lds[row*RS + cbase] = o2;
        }
    }

    // ---------- Phase C: gather prior -> x_lds[s][80..159] ----------
    {
        const float4* feats4 = (const float4*)feats;
        #pragma unroll
        for (int q = 0; q < 5; ++q) {
            float ax=0.f, ay=0.f, az=0.f, aw=0.f;
            #pragma unroll
            for (int k = 0; k < 8; ++k) {
                if (pi[k] >= 0) {
                    float4 f = feats4[pi[k]*20 + quarter*5 + q];
                    ax += wt[k]*f.x; ay += wt[k]*f.y;
                    az += wt[k]*f.z; aw += wt[k]*f.w;
                }
            }
            int c = 80 + quarter*20 + q*4;
            ushort4 pk = make_ushort4(f2bf(ax), f2bf(ay), f2bf(az), f2bf(aw));
            *(ushort4*)&x_lds[sl*RS + c] = pk;   // 8 B, aligned
        }
    }

    __syncthreads();

    // ---------- Phase D: MFMA GEMM  y[o][s] = sum_c W[o][c] * x[c][s] ----------
    const int wave = tid >> 6, lane = tid & 63;
    const int lrow = lane & 15, lgrp = lane >> 4;

    f32x4 acc[5];
    #pragma unroll
    for (int mt = 0; mt < 5; ++mt) acc[mt] = (f32x4){0.f, 0.f, 0.f, 0.f};

    const int srow = (wave*16 + lrow) * RS;   // each wave owns a 16-s tile

    #pragma unroll
    for (int ks = 0; ks < 5; ++ks) {
        s16x8 b = *(const s16x8*)&x_lds[srow + ks*32 + lgrp*8];
        #pragma unroll
        for (int mt = 0; mt < 5; ++mt) {
            s16x8 a = *(const s16x8*)&wfrag[((mt*5 + ks)*64 + lane)*8];
            acc[mt] = __builtin_amdgcn_mfma_f32_16x16x32_bf16(a, b, acc[mt], 0, 0, 0);
        }
    }

    // ---------- Epilogue: BN + residual(from LDS bf16) + ReLU ----------
    const int slocal = wave*16 + lrow;
    const int sglob  = sbase + slocal;
    #pragma unroll
    for (int mt = 0; mt < 5; ++mt) {
        #pragma unroll
        for (int r = 0; r < 4; ++r) {
            int o = mt*16 + lgrp*4 + r;
            float2 ss = bnss[o];
            float resid = __builtin_bit_cast(float, (uint)x_lds[slocal*RS + o] << 16);
            float v = acc[mt][r]*ss.x + ss.y + resid;
            out[o*SPATIAL + sglob] = fmaxf(v, 0.f);
        }
    }
}

extern "C" void kernel_launch(void* const* d_in, const int* in_sizes, int n_in,
                              void* d_out, int out_size, void* d_ws, size_t ws_size,
                              hipStream_t stream) {
    const float* bev    = (const float*)d_in[0];
    const int*   coords = (const int*)  d_in[1];
    const float* feats  = (const float*)d_in[2];
    const float* wconv  = (const float*)d_in[3];
    const float* bconv  = (const float*)d_in[4];
    const float* gamma  = (const float*)d_in[5];
    const float* beta   = (const float*)d_in[6];
    const float* mean   = (const float*)d_in[7];
    const float* var    = (const float*)d_in[8];
    float*       out    = (float*)d_out;

    int*    winner = (int*)d_ws;                                      // 5,242,880 B
    ushort* wfrag  = (ushort*)((char*)d_ws + (size_t)NVOX*4);         // 25,600 B
    float2* bnss   = (float2*)((char*)d_ws + (size_t)NVOX*4 + 25600); // 640 B
    int npts = in_sizes[1] / 4;

    hipLaunchKernelGGL(init_winner_k, dim3((NVOX + 255)/256), dim3(256), 0, stream, winner);
    hipLaunchKernelGGL(scatter_k, dim3((npts + 255)/256), dim3(256), 0, stream,
                       coords, npts, winner);
    hipLaunchKernelGGL(prep_k, dim3(1), dim3(256), 0, stream,
                       wconv, bconv, gamma, beta, mean, var, wfrag, bnss);
    hipLaunchKernelGGL(fused_k, dim3(NWG), dim3(512), 0, stream,
                       bev, feats, winner, wfrag, bnss, out);
}

// Round 5
// 208.561 us; speedup vs baseline: 5.7503x; 1.1053x over previous
//
#include <hip/hip_runtime.h>
#include <hip/hip_bf16.h>

#define VXX 256
#define VYY 256
#define VZZ 20
#define NC  80
#define OH  200
#define OW  200
#define OZ  16
#define SPATIAL (OH*OW*OZ)      // 640000
#define NVOX (VXX*VYY*VZZ)      // 1310720
#define EPSV 1e-5f
#define NS 64                   // spatial positions per block
#define RS 168                  // x_lds row stride in bf16 elems (336 B)
#define NWG (SPATIAL/NS)        // 10000 blocks

typedef float  f32x4 __attribute__((ext_vector_type(4)));
typedef short  s16x8 __attribute__((ext_vector_type(8)));

__device__ __forceinline__ ushort f2bf(float f) {
    uint u = __builtin_bit_cast(uint, f);
    u += 0x7FFFu + ((u >> 16) & 1u);     // round-to-nearest-even
    return (ushort)(u >> 16);
}

__global__ void init_winner_k(int* __restrict__ w) {
    int i = blockIdx.x * 256 + threadIdx.x;
    if (i < NVOX) w[i] = -1;
}

__global__ void scatter_k(const int* __restrict__ coords, int npts,
                          int* __restrict__ winner) {
    int i = blockIdx.x * 256 + threadIdx.x;
    if (i >= npts) return;
    int b = coords[i*4+0];
    int x = coords[i*4+1];
    int y = coords[i*4+2];
    int z = coords[i*4+3];
    int vi = ((b*VXX + x)*VYY + y)*VZZ + z;
    atomicMax(&winner[vi], i);   // max point index == last write wins
}

// Pack W (80x160 fp32) into bf16 MFMA A-fragment order; fold BN into (scale, shift).
// Fragment f = mt*5+ks holds A[o = mt*16 + (l&15)][c = ks*32 + (l>>4)*8 + j].
__global__ void prep_k(const float* __restrict__ wconv,
                       const float* __restrict__ bconv,
                       const float* __restrict__ gamma,
                       const float* __restrict__ beta,
                       const float* __restrict__ mean,
                       const float* __restrict__ var,
                       ushort* __restrict__ wfrag,
                       float2* __restrict__ bnss) {
    int tid = threadIdx.x;
    for (int idx = tid; idx < 25*512; idx += 256) {
        int f   = idx >> 9;
        int rem = idx & 511;
        int l   = rem >> 3;
        int j   = rem & 7;
        int mt  = f / 5;
        int ks  = f - mt*5;
        int o   = mt*16 + (l & 15);
        int c   = ks*32 + (l >> 4)*8 + j;
        wfrag[idx] = f2bf(wconv[o*160 + c]);
    }
    if (tid < NC) {
        float inv = gamma[tid] * rsqrtf(var[tid] + EPSV);
        bnss[tid] = make_float2(inv, bconv[tid]*inv + beta[tid] - mean[tid]*inv);
    }
}

__launch_bounds__(256, 5)
__global__ void fused_k(const float* __restrict__ bev,
                        const float* __restrict__ feats,
                        const int*  __restrict__ winner,
                        const ushort* __restrict__ wfrag,
                        const float2* __restrict__ bnss,
                        float* __restrict__ out) {
    __shared__ __align__(16) ushort x_lds[NS * RS];   // [s][c] bf16, 21 KB

    const int tid   = threadIdx.x;
    // XCD-aware bijective swizzle: 10000 % 8 == 0 -> each XCD gets 1250
    // consecutive tiles (25 full h-rows).
    const int bid   = blockIdx.x;
    const int swzb  = (bid & 7) * (NWG/8) + (bid >> 3);
    const int sbase = swzb * NS;
    const int sl    = tid & 63;         // spatial position within tile
    const int quarter = tid >> 6;       // 0..3 -> 20 prior channels each

    // ---------- Phase A: tap geometry; ISSUE winner gather early ----------
    int pi[8]; float wt[8];
    {
        const int S = sbase + sl;
        const int z = S & 15;
        const int w = (S >> 4) % OW;
        const int h = S / (OW * OZ);     // uniform within block (3200 % 64 == 0)

        float posy = (h + 0.5f) * ((float)VYY/(float)OH) - 0.5f;
        posy = fminf(fmaxf(posy, 0.f), (float)(VYY-1));
        int y0 = (int)posy; int y1 = min(y0+1, VYY-1); float fy = posy - (float)y0;
        float posx = (w + 0.5f) * ((float)VXX/(float)OW) - 0.5f;
        posx = fminf(fmaxf(posx, 0.f), (float)(VXX-1));
        int x0 = (int)posx; int x1 = min(x0+1, VXX-1); float fx = posx - (float)x0;
        float posz = (z + 0.5f) * ((float)VZZ/(float)OZ) - 0.5f;
        posz = fminf(fmaxf(posz, 0.f), (float)(VZZ-1));
        int z0 = (int)posz; int z1 = min(z0+1, VZZ-1); float fz = posz - (float)z0;

        #pragma unroll
        for (int k = 0; k < 8; ++k) {
            int kz = k & 1, kx = (k>>1)&1, ky = k>>2;
            int yy = ky ? y1 : y0, xx = kx ? x1 : x0, zz = kz ? z1 : z0;
            pi[k] = winner[(xx*VYY + yy)*VZZ + zz];
            wt[k] = (ky?fy:1.f-fy) * (kx?fx:1.f-fx) * (kz?fz:1.f-fz);
        }
    }

    // ---------- Phase C prologue: issue tap-0 feats row loads NOW ----------
    const float4* feats4 = (const float4*)feats;
    const int cq = quarter * 5;          // float4 offset within a point's 20-f4 row
    float4 fb0[5], fb1[5];
    if (pi[0] >= 0) {
        const float4* p = feats4 + pi[0]*20 + cq;
        #pragma unroll
        for (int q = 0; q < 5; ++q) fb0[q] = p[q];
    }

    // ---------- Phase B: bev -> x_lds[s][0..79], shfl-transposed ----------
    // (tap-0 gather latency hides under this)
    {
        const int wv = tid >> 6, ln = tid & 63;
        const int q16 = ln & 15, mm = ln >> 4;
        #pragma unroll
        for (int it = 0; it < 5; ++it) {
            int g     = it*4 + wv;          // 0..19 channel-quads
            int cbase = g * 4;              // 0,4,...,76
            const float4 v = *(const float4*)&bev[(cbase+mm)*SPATIAL + sbase + q16*4];
            uint u0 = (uint)f2bf(v.x) | ((uint)f2bf(v.y) << 16);
            uint u1 = (uint)f2bf(v.z) | ((uint)f2bf(v.w) << 16);
            uint us[4];
            #pragma unroll
            for (int j = 0; j < 4; ++j) {
                int src = q16 + 16*j;
                uint t0 = (uint)__shfl((int)u0, src, 64);
                uint t1 = (uint)__shfl((int)u1, src, 64);
                uint sel = (mm & 2) ? t1 : t0;
                us[j] = (mm & 1) ? (sel >> 16) : (sel & 0xffffu);
            }
            uint2 o2 = make_uint2(us[0] | (us[1] << 16), us[2] | (us[3] << 16));
            int row = q16*4 + mm;
            *(uint2*)&x_lds[row*RS + cbase] = o2;
        }
    }

    // ---------- Phase C: software-pipelined tap gather -> x_lds[s][80..159] ----------
    {
        float4 s4[5];
        #pragma unroll
        for (int q = 0; q < 5; ++q) s4[q] = (float4){0.f, 0.f, 0.f, 0.f};

        #pragma unroll
        for (int k = 0; k < 8; ++k) {
            if (k + 1 < 8 && pi[k+1] >= 0) {       // prefetch next tap's row
                const float4* p = feats4 + pi[k+1]*20 + cq;
                #pragma unroll
                for (int q = 0; q < 5; ++q) {
                    if (k & 1) fb0[q] = p[q]; else fb1[q] = p[q];
                }
            }
            if (pi[k] >= 0) {
                float wk = wt[k];
                #pragma unroll
                for (int q = 0; q < 5; ++q) {
                    float4 f = (k & 1) ? fb1[q] : fb0[q];
                    s4[q].x += wk * f.x; s4[q].y += wk * f.y;
                    s4[q].z += wk * f.z; s4[q].w += wk * f.w;
                }
            }
        }

        #pragma unroll
        for (int q = 0; q < 5; ++q) {
            int c = 80 + quarter*20 + q*4;
            ushort4 pk = make_ushort4(f2bf(s4[q].x), f2bf(s4[q].y),
                                      f2bf(s4[q].z), f2bf(s4[q].w));
            *(ushort4*)&x_lds[sl*RS + c] = pk;   // 8 B, aligned
        }
    }

    __syncthreads();

    // ---------- Phase D: MFMA GEMM  y[o][s] = sum_c W[o][c] * x[c][s] ----------
    const int wave = tid >> 6, lane = tid & 63;
    const int lrow = lane & 15, lgrp = lane >> 4;

    f32x4 acc[5];
    #pragma unroll
    for (int mt = 0; mt < 5; ++mt) acc[mt] = (f32x4){0.f, 0.f, 0.f, 0.f};

    const int srow = (wave*16 + lrow) * RS;   // each wave owns a 16-s tile

    #pragma unroll
    for (int ks = 0; ks < 5; ++ks) {
        s16x8 b = *(const s16x8*)&x_lds[srow + ks*32 + lgrp*8];
        #pragma unroll
        for (int mt = 0; mt < 5; ++mt) {
            s16x8 a = *(const s16x8*)&wfrag[((mt*5 + ks)*64 + lane)*8];
            acc[mt] = __builtin_amdgcn_mfma_f32_16x16x32_bf16(a, b, acc[mt], 0, 0, 0);
        }
    }

    // ---------- Epilogue: BN + residual(from LDS bf16) + ReLU ----------
    const int slocal = wave*16 + lrow;
    const int sglob  = sbase + slocal;
    #pragma unroll
    for (int mt = 0; mt < 5; ++mt) {
        #pragma unroll
        for (int r = 0; r < 4; ++r) {
            int o = mt*16 + lgrp*4 + r;
            float2 ss = bnss[o];
            float resid = __builtin_bit_cast(float, (uint)x_lds[slocal*RS + o] << 16);
            float v = acc[mt][r]*ss.x + ss.y + resid;
            out[o*SPATIAL + sglob] = fmaxf(v, 0.f);
        }
    }
}

extern "C" void kernel_launch(void* const* d_in, const int* in_sizes, int n_in,
                              void* d_out, int out_size, void* d_ws, size_t ws_size,
                              hipStream_t stream) {
    const float* bev    = (const float*)d_in[0];
    const int*   coords = (const int*)  d_in[1];
    const float* feats  = (const float*)d_in[2];
    const float* wconv  = (const float*)d_in[3];
    const float* bconv  = (const float*)d_in[4];
    const float* gamma  = (const float*)d_in[5];
    const float* beta   = (const float*)d_in[6];
    const float* mean   = (const float*)d_in[7];
    const float* var    = (const float*)d_in[8];
    float*       out    = (float*)d_out;

    int*    winner = (int*)d_ws;                                      // 5,242,880 B
    ushort* wfrag  = (ushort*)((char*)d_ws + (size_t)NVOX*4);         // 25,600 B
    float2* bnss   = (float2*)((char*)d_ws + (size_t)NVOX*4 + 25600); // 640 B
    int npts = in_sizes[1] / 4;

    hipLaunchKernelGGL(init_winner_k, dim3((NVOX + 255)/256), dim3(256), 0, stream, winner);
    hipLaunchKernelGGL(scatter_k, dim3((npts + 255)/256), dim3(256), 0, stream,
                       coords, npts, winner);
    hipLaunchKernelGGL(prep_k, dim3(1), dim3(256), 0, stream,
                       wconv, bconv, gamma, beta, mean, var, wfrag, bnss);
    hipLaunchKernelGGL(fused_k, dim3(NWG), dim3(256), 0, stream,
                       bev, feats, winner, wfrag, bnss, out);
}